// Round 4
// baseline (1115.313 us; speedup 1.0000x reference)
//
#include <hip/hip_runtime.h>
#include <stdint.h>

// ============================================================================
// ScannedMultiLayerLSTM: T=64, B=32, W=1024, L=4
// Round 4: flag-gated CACHED exchange.
//   - 256 blocks (1/CU); block -> (layer = (b&7)&3, slice s2 of 16 hidden units)
//     => under round-robin blockIdx%8->XCD mapping, each layer lives on 2 XCDs
//        so consumer blocks share exchanged lines via L2 (perf-only heuristic).
//   - hist is CHUNKED: hist[l][t][s2][32b][16n] -- each producer block owns one
//     contiguous 1KB chunk (single writer).
//   - publish: write-through stores + vmcnt(0) + barrier + flag[l][t][s2]=1.
//   - consume: poll 64 flags (4B bypass loads, wave0=srcY, wave2=srcH), then
//     barrier, then PLAIN CACHED loads of the data (never cached pre-flag =>
//     no stale-line hazard, correct for any XCD mapping).
//   - weights preloaded into regs once; c-state in regs; LDS cross-wave reduce.
// ============================================================================

typedef unsigned short u16;
typedef unsigned int u32;
typedef __attribute__((ext_vector_type(8))) short short8;
typedef __attribute__((ext_vector_type(4))) float f32x4;

#define NT 64
#define NB 32
#define NW 1024
#define NLAY 4
#define G4 4096

// workspace layout (bytes)
#define HIST_OFF 0                 // bf16 hist[L][65][64][32][16] chunked
#define FLAGS_OFF 17039360         // u32 flags[L][T][64] (65536 B)
#define RMASK_OFF 17104896         // int rmask[T][B] (8192 B)
#define MODE_OFF 17113088          // int modes[2]

__device__ __forceinline__ float bf2f(u16 u) {
  union { u32 i; float f; } v; v.i = ((u32)u) << 16; return v.f;
}
__device__ __forceinline__ u16 f2bf(float f) {
  union { float f; u32 i; } v; v.f = f;
  u32 b = v.i;
  return (u16)((b + 0x7FFFu + ((b >> 16) & 1u)) >> 16);
}
__device__ __forceinline__ float sigmoidf_(float x) { return 1.f / (1.f + __expf(-x)); }
__device__ __forceinline__ float tanhfast(float x) {
  float cx = fminf(fmaxf(x, -15.f), 15.f);
  float e = __expf(2.f * cx);
  return (e - 1.f) / (e + 1.f);
}

// cache-bypassing 4B load (MALL-coherent)
__device__ __forceinline__ u32 poll_load(const u32* p) {
  u32 v;
  asm volatile("global_load_dword %0, %1, off sc0 sc1" : "=v"(v) : "v"(p));
  asm volatile("s_waitcnt vmcnt(0)" : "+v"(v) : : "memory");
  return v;
}

// ---------------------------------------------------------------------------
// setup: detect dtypes, normalize resets, zero flags. 1 block x 256 threads.
// ---------------------------------------------------------------------------
__global__ void lstm_setup(const void* __restrict__ x, const void* __restrict__ resets,
                           int* __restrict__ modes, int* __restrict__ rmask,
                           u32* __restrict__ flags) {
  __shared__ int votes_bf16, bad_int, bad_float;
  __shared__ int sm_rmode;
  int tid = threadIdx.x;
  if (tid == 0) { votes_bf16 = 0; bad_int = 0; bad_float = 0; }
  __syncthreads();
  {
    u32 w = ((const u32*)x)[tid];
    int e = (int)((w >> 7) & 0xFFu);
    if (e >= 100 && e <= 140) atomicAdd(&votes_bf16, 1);
  }
  if (tid < 128) {
    u32 r = ((const u32*)resets)[tid];
    if (r > 1u) atomicAdd(&bad_int, 1);
    if (r != 0u && r != 0x3F800000u) atomicAdd(&bad_float, 1);
  }
  __syncthreads();
  if (tid == 0) {
    int mbf = (votes_bf16 >= 192) ? 1 : 0;
    int rmode;
    if (bad_int == 0) rmode = 1;
    else if (bad_float == 0) rmode = 2;
    else rmode = 0;
    modes[0] = mbf;
    modes[1] = rmode;
    sm_rmode = rmode;
  }
  __syncthreads();
  int rmode = sm_rmode;
#pragma unroll
  for (int k = 0; k < 8; ++k) {
    int idx = tid * 8 + k;
    int val;
    if (rmode == 1) val = (((const int*)resets)[idx] != 0);
    else if (rmode == 2) val = (((const u32*)resets)[idx] != 0u);
    else val = (((const unsigned char*)resets)[idx] != 0);
    rmask[idx] = val;
  }
  for (int k = tid; k < NLAY * NT * 64; k += 256) flags[k] = 0;
}

// ---------------------------------------------------------------------------
// prep: copy h0 -> hist slot0 (bf16, chunked layout). 512 blocks x 256.
// ---------------------------------------------------------------------------
template <bool BF16>
__global__ void lstm_prep(const void* __restrict__ h0, const int* __restrict__ modes,
                          u16* __restrict__ hist) {
  if ((modes[0] != 0) != BF16) return;
  int idx = blockIdx.x * 256 + threadIdx.x; // 0..131071 over [L][B][W]
  int l = idx >> 15;
  int rem = idx & 32767;
  int b = rem >> 10;
  int w = rem & 1023;
  float hv;
  if (BF16) hv = bf2f(((const u16*)h0)[idx]);
  else      hv = ((const float*)h0)[idx];
  // chunked: [l][slot=0][s2 = w>>4][b][n = w&15]
  size_t dst = (((size_t)l * 65 + 0) * 64 + (w >> 4)) * 512 + (size_t)b * 16 + (w & 15);
  hist[dst] = f2bf(hv);
}

// ---------------------------------------------------------------------------
// main persistent kernel. 256 blocks x 256 threads (4 waves).
// ---------------------------------------------------------------------------
template <bool BF16>
__global__ __launch_bounds__(256, 1) void lstm_main(
    const void* __restrict__ xv, const void* __restrict__ Wxv,
    const void* __restrict__ Whv, const void* __restrict__ biasv,
    const void* __restrict__ c0v,
    void* __restrict__ outv, const int* __restrict__ modes,
    const int* __restrict__ rmask, u16* __restrict__ hist,
    u32* __restrict__ flags) {
  if ((modes[0] != 0) != BF16) return;

  // XCD-local decode: xcd = b&7 (round-robin heuristic), layer = xcd&3.
  const int xcd = blockIdx.x & 7;
  const int l = xcd & 3;
  const int s2 = (blockIdx.x >> 3) + ((xcd >> 2) << 5); // 0..63
  const int hb = s2 * 16;
  const int tid = threadIdx.x;
  const int wave = tid >> 6;
  const int lane = tid & 63;
  const bool xpart = (wave < 2);      // waves 0,1: y@Wx half; waves 2,3: h@Wh half
  const int krel = (wave & 1) * 512;  // K offset within this half's 1024 rows
  const int lrow = lane & 15;
  const int lk8 = (lane >> 4) * 8;

  // epilogue mapping: thread -> 2 adjacent n for one b
  const int eb = tid >> 3;            // 0..31  (batch row)
  const int n0 = (tid & 7) * 2;       // 0,2,..,14
  const int emt = eb >> 4, er = eb & 15;

  __shared__ float red[4][2][4][16][17]; // [wave][mtile][gate][row][col(+pad)]

  // ---- one-time weight preload: B-fragments B[k][n], n=lane&15, k=lk8+j ----
  short8 wfrag[4][16]; // [gate][ktile]
  {
    const size_t base = (size_t)l * NW * G4;
#pragma unroll
    for (int g = 0; g < 4; ++g) {
#pragma unroll
      for (int kt = 0; kt < 16; ++kt) {
        size_t off = base + (size_t)(krel + kt * 32 + lk8) * G4 + (size_t)(g * 1024 + hb + lrow);
        short8 v;
        if (BF16) {
          const u16* p = (xpart ? (const u16*)Wxv : (const u16*)Whv) + off;
#pragma unroll
          for (int j = 0; j < 8; ++j) v[j] = (short)p[(size_t)j * G4];
        } else {
          const float* p = (xpart ? (const float*)Wxv : (const float*)Whv) + off;
#pragma unroll
          for (int j = 0; j < 8; ++j) v[j] = (short)f2bf(p[(size_t)j * G4]);
        }
        wfrag[g][kt] = v;
      }
    }
  }

  // ---- bias preload for this thread's 2 cells ----
  float bias_r[4][2];
#pragma unroll
  for (int g = 0; g < 4; ++g)
#pragma unroll
    for (int j = 0; j < 2; ++j) {
      int bidx = l * G4 + g * 1024 + hb + n0 + j;
      bias_r[g][j] = BF16 ? bf2f(((const u16*)biasv)[bidx]) : ((const float*)biasv)[bidx];
    }

  float creg[2] = {0.f, 0.f};

  short8 z8;
#pragma unroll
  for (int j = 0; j < 8; ++j) z8[j] = 0;

#pragma unroll 1
  for (int t = 0; t < NT; ++t) {
    // ---- poll phase: tiny bypass flag polls only ----
    if (wave == 0 && l > 0) {
      const u32* fp = &flags[((size_t)(l - 1) * NT + t) * 64 + lane];
      while (poll_load(fp) == 0) __builtin_amdgcn_s_sleep(1);
    }
    if (wave == 2 && t > 0) {
      const u32* fp = &flags[((size_t)l * NT + (t - 1)) * 64 + lane];
      while (poll_load(fp) == 0) __builtin_amdgcn_s_sleep(1);
    }
    __syncthreads();   // gate: no cacheable hist read before flags confirmed

    // ---- A sources (chunked layout) ----
    const u16* srcH = hist + ((size_t)l * 65 + t) * (64 * 512);             // h[l][t-1]
    const u16* srcY = hist + ((size_t)(l - 1) * 65 + (t + 1)) * (64 * 512); // h[l-1][t]
    const u16* srcXb = (const u16*)xv + (size_t)t * NB * NW;
    const float* srcXf = (const float*)xv + (size_t)t * NB * NW;

    int rm0 = 0, rm1 = 0;
    if (!xpart) {
      rm0 = rmask[t * NB + lrow];
      rm1 = rmask[t * NB + 16 + lrow];
    }

    f32x4 acc[2][4];
    f32x4 zf = {0.f, 0.f, 0.f, 0.f};
#pragma unroll
    for (int mt = 0; mt < 2; ++mt)
#pragma unroll
      for (int g = 0; g < 4; ++g) acc[mt][g] = zf;

#pragma unroll
    for (int half = 0; half < 2; ++half) {
      short8 af[8][2];
#pragma unroll
      for (int q = 0; q < 8; ++q) {
        int k = krel + (half * 8 + q) * 32 + lk8;
        short8 a0, a1;
        if (!xpart || l > 0) {
          const u16* src = xpart ? srcY : srcH;
          const u16* pc = src + (size_t)(k >> 4) * 512 + (k & 15);
          a0 = *(const short8*)(pc + lrow * 16);
          a1 = *(const short8*)(pc + (lrow + 16) * 16);
          if (!xpart) {
            if (rm0) a0 = z8;
            if (rm1) a1 = z8;
          }
        } else if (BF16) {
          a0 = *(const short8*)(srcXb + (size_t)lrow * NW + k);
          a1 = *(const short8*)(srcXb + (size_t)(lrow + 16) * NW + k);
        } else {
          const f32x4* p0 = (const f32x4*)(srcXf + (size_t)lrow * NW + k);
          const f32x4* p1 = (const f32x4*)(srcXf + (size_t)(lrow + 16) * NW + k);
          f32x4 x0a = p0[0], x0b = p0[1], x1a = p1[0], x1b = p1[1];
#pragma unroll
          for (int j = 0; j < 4; ++j) {
            a0[j] = (short)f2bf(x0a[j]);
            a0[j + 4] = (short)f2bf(x0b[j]);
            a1[j] = (short)f2bf(x1a[j]);
            a1[j + 4] = (short)f2bf(x1b[j]);
          }
        }
        af[q][0] = a0;
        af[q][1] = a1;
      }
#pragma unroll
      for (int q = 0; q < 8; ++q) {
        const int kt = half * 8 + q;
#pragma unroll
        for (int g = 0; g < 4; ++g) {
          acc[0][g] = __builtin_amdgcn_mfma_f32_16x16x32_bf16(af[q][0], wfrag[g][kt], acc[0][g], 0, 0, 0);
          acc[1][g] = __builtin_amdgcn_mfma_f32_16x16x32_bf16(af[q][1], wfrag[g][kt], acc[1][g], 0, 0, 0);
        }
      }
    }

    // ---- cross-wave reduce via LDS ----
#pragma unroll
    for (int mt = 0; mt < 2; ++mt)
#pragma unroll
      for (int g = 0; g < 4; ++g)
#pragma unroll
        for (int r2 = 0; r2 < 4; ++r2)
          red[wave][mt][g][(lane >> 4) * 4 + r2][lrow] = acc[mt][g][r2];
    __syncthreads();

    // ---- epilogue: this thread's 2 cells (eb, n0) (eb, n0+1) ----
    float hn[2];
    {
      int rm = rmask[t * NB + eb];
#pragma unroll
      for (int j = 0; j < 2; ++j) {
        int n = n0 + j;
        float gv[4];
#pragma unroll
        for (int g = 0; g < 4; ++g)
          gv[g] = red[0][emt][g][er][n] + red[1][emt][g][er][n] +
                  red[2][emt][g][er][n] + red[3][emt][g][er][n] + bias_r[g][j];
        float c_old = creg[j];
        if (t == 0) {
          int cidx = (l * NB + eb) * NW + hb + n;
          c_old = BF16 ? bf2f(((const u16*)c0v)[cidx]) : ((const float*)c0v)[cidx];
        }
        if (rm) c_old = 0.f;
        float ci = sigmoidf_(gv[0]);
        float cf = sigmoidf_(gv[1]);
        float cg = tanhfast(gv[2]);
        float co = sigmoidf_(gv[3]);
        float cn = cf * c_old + ci * cg;
        hn[j] = co * tanhfast(cn);
        creg[j] = cn;
      }
      // publish h chunk (write-through, packed 2x bf16): 256 threads cover 1KB
      u32 hp = (u32)f2bf(hn[0]) | ((u32)f2bf(hn[1]) << 16);
      size_t hoff = (((size_t)l * 65 + (t + 1)) * 64 + s2) * 512 + (size_t)eb * 16 + n0;
      __hip_atomic_store((u32*)(hist + hoff), hp, __ATOMIC_RELAXED, __HIP_MEMORY_SCOPE_AGENT);
      // y output (layer 3)
      if (l == NLAY - 1) {
        size_t oy = ((size_t)t * NB + eb) * NW + hb + n0;
        if (BF16) ((u32*)outv)[oy >> 1] = hp;
        else { ((float*)outv)[oy] = hn[0]; ((float*)outv)[oy + 1] = hn[1]; }
      }
      // final c/h outputs
      if (t == NT - 1) {
        size_t oc = (size_t)NT * NB * NW + ((size_t)l * NB + eb) * NW + hb + n0;
        size_t oh = oc + (size_t)NLAY * NB * NW;
        if (BF16) {
          u32 cp = (u32)f2bf(creg[0]) | ((u32)f2bf(creg[1]) << 16);
          ((u32*)outv)[oc >> 1] = cp;
          ((u32*)outv)[oh >> 1] = hp;
        } else {
          ((float*)outv)[oc] = creg[0];
          ((float*)outv)[oc + 1] = creg[1];
          ((float*)outv)[oh] = hn[0];
          ((float*)outv)[oh + 1] = hn[1];
        }
      }
    }

    // ---- drain own stores, then one flag store per block ----
    asm volatile("s_waitcnt vmcnt(0)" ::: "memory");
    __syncthreads();  // all chunk stores MALL-acked; also protects red[]
    if (tid == 0)
      __hip_atomic_store(&flags[((size_t)l * NT + t) * 64 + s2], 1u,
                         __ATOMIC_RELAXED, __HIP_MEMORY_SCOPE_AGENT);
  }
}

// ---------------------------------------------------------------------------
extern "C" void kernel_launch(void* const* d_in, const int* in_sizes, int n_in,
                              void* d_out, int out_size, void* d_ws, size_t ws_size,
                              hipStream_t stream) {
  const void* x = d_in[0];
  const void* resets = d_in[1];
  const void* c0 = d_in[2];
  const void* h0 = d_in[3];
  const void* Wx = d_in[4];
  const void* Wh = d_in[5];
  const void* bias = d_in[6];

  char* ws = (char*)d_ws;
  u16* hist = (u16*)(ws + HIST_OFF);
  u32* flags = (u32*)(ws + FLAGS_OFF);
  int* rmask = (int*)(ws + RMASK_OFF);
  int* modes = (int*)(ws + MODE_OFF);

  lstm_setup<<<1, 256, 0, stream>>>(x, resets, modes, rmask, flags);
  lstm_prep<true><<<512, 256, 0, stream>>>(h0, modes, hist);
  lstm_prep<false><<<512, 256, 0, stream>>>(h0, modes, hist);
  lstm_main<true><<<256, 256, 0, stream>>>(x, Wx, Wh, bias, c0, d_out, modes, rmask, hist, flags);
  lstm_main<false><<<256, 256, 0, stream>>>(x, Wx, Wh, bias, c0, d_out, modes, rmask, hist, flags);
}

// Round 5
// 1085.814 us; speedup vs baseline: 1.0272x; 1.0272x over previous
//
#include <hip/hip_runtime.h>
#include <stdint.h>

// ============================================================================
// ScannedMultiLayerLSTM: T=64, B=32, W=1024, L=4
// Round 5: flag-gated cached exchange with EXPLICIT WRITE-THROUGH publishes.
//   Theory: __hip_atomic_store(RELAXED, AGENT) emitted write-back L2 stores;
//   cross-XCD visibility waited on L2 eviction (~10us) => constant ~15us hops
//   in rounds 2-4. Fix: publish hist chunks + flags with inline-asm
//   `global_store_dword ... sc0 sc1` (write-through to coherent point).
//   - 256 blocks (1/CU); block -> (layer = (b&7)&3, slice s2 of 16 units)
//   - hist CHUNKED: hist[l][t][s2][32b][16n], single writer per 1KB chunk
//   - publish: sc0sc1 stores + vmcnt(0) + barrier + sc0sc1 flag
//   - consume: each wave spin-polls (bypass loads) only the flags gating ITS
//     loads, then plain cached loads (first touch is post-flag => never stale)
//   - weights in VGPRs; c-state in regs; LDS cross-wave reduce
// ============================================================================

typedef unsigned short u16;
typedef unsigned int u32;
typedef __attribute__((ext_vector_type(8))) short short8;
typedef __attribute__((ext_vector_type(4))) float f32x4;

#define NT 64
#define NB 32
#define NW 1024
#define NLAY 4
#define G4 4096

// workspace layout (bytes)
#define HIST_OFF 0                 // bf16 hist[L][65][64][32][16] chunked
#define FLAGS_OFF 17039360         // u32 flags[L][T][64] (65536 B)
#define RMASK_OFF 17104896         // int rmask[T][B] (8192 B)
#define MODE_OFF 17113088          // int modes[2]

__device__ __forceinline__ float bf2f(u16 u) {
  union { u32 i; float f; } v; v.i = ((u32)u) << 16; return v.f;
}
__device__ __forceinline__ u16 f2bf(float f) {
  union { float f; u32 i; } v; v.f = f;
  u32 b = v.i;
  return (u16)((b + 0x7FFFu + ((b >> 16) & 1u)) >> 16);
}
__device__ __forceinline__ float sigmoidf_(float x) { return 1.f / (1.f + __expf(-x)); }
__device__ __forceinline__ float tanhfast(float x) {
  float cx = fminf(fmaxf(x, -15.f), 15.f);
  float e = __expf(2.f * cx);
  return (e - 1.f) / (e + 1.f);
}

// cache-bypassing 4B load (coherent-point read)
__device__ __forceinline__ u32 poll_load(const u32* p) {
  u32 v;
  asm volatile("global_load_dword %0, %1, off sc0 sc1" : "=v"(v) : "v"(p));
  asm volatile("s_waitcnt vmcnt(0)" : "+v"(v) : : "memory");
  return v;
}
// write-through 4B store (updates L2 on the way, lands at coherent point)
__device__ __forceinline__ void publish_store(u32* p, u32 v) {
  asm volatile("global_store_dword %0, %1, off sc0 sc1" : : "v"(p), "v"(v) : "memory");
}

// ---------------------------------------------------------------------------
// setup: detect dtypes, normalize resets, zero flags. 1 block x 256 threads.
// ---------------------------------------------------------------------------
__global__ void lstm_setup(const void* __restrict__ x, const void* __restrict__ resets,
                           int* __restrict__ modes, int* __restrict__ rmask,
                           u32* __restrict__ flags) {
  __shared__ int votes_bf16, bad_int, bad_float;
  __shared__ int sm_rmode;
  int tid = threadIdx.x;
  if (tid == 0) { votes_bf16 = 0; bad_int = 0; bad_float = 0; }
  __syncthreads();
  {
    u32 w = ((const u32*)x)[tid];
    int e = (int)((w >> 7) & 0xFFu);
    if (e >= 100 && e <= 140) atomicAdd(&votes_bf16, 1);
  }
  if (tid < 128) {
    u32 r = ((const u32*)resets)[tid];
    if (r > 1u) atomicAdd(&bad_int, 1);
    if (r != 0u && r != 0x3F800000u) atomicAdd(&bad_float, 1);
  }
  __syncthreads();
  if (tid == 0) {
    int mbf = (votes_bf16 >= 192) ? 1 : 0;
    int rmode;
    if (bad_int == 0) rmode = 1;
    else if (bad_float == 0) rmode = 2;
    else rmode = 0;
    modes[0] = mbf;
    modes[1] = rmode;
    sm_rmode = rmode;
  }
  __syncthreads();
  int rmode = sm_rmode;
#pragma unroll
  for (int k = 0; k < 8; ++k) {
    int idx = tid * 8 + k;
    int val;
    if (rmode == 1) val = (((const int*)resets)[idx] != 0);
    else if (rmode == 2) val = (((const u32*)resets)[idx] != 0u);
    else val = (((const unsigned char*)resets)[idx] != 0);
    rmask[idx] = val;
  }
  for (int k = tid; k < NLAY * NT * 64; k += 256) flags[k] = 0;
}

// ---------------------------------------------------------------------------
// prep: copy h0 -> hist slot0 (bf16, chunked layout). 512 blocks x 256.
// ---------------------------------------------------------------------------
template <bool BF16>
__global__ void lstm_prep(const void* __restrict__ h0, const int* __restrict__ modes,
                          u16* __restrict__ hist) {
  if ((modes[0] != 0) != BF16) return;
  int idx = blockIdx.x * 256 + threadIdx.x; // 0..131071 over [L][B][W]
  int l = idx >> 15;
  int rem = idx & 32767;
  int b = rem >> 10;
  int w = rem & 1023;
  float hv;
  if (BF16) hv = bf2f(((const u16*)h0)[idx]);
  else      hv = ((const float*)h0)[idx];
  size_t dst = (((size_t)l * 65 + 0) * 64 + (w >> 4)) * 512 + (size_t)b * 16 + (w & 15);
  hist[dst] = f2bf(hv);
}

// ---------------------------------------------------------------------------
// main persistent kernel. 256 blocks x 256 threads (4 waves).
// ---------------------------------------------------------------------------
template <bool BF16>
__global__ __launch_bounds__(256, 1) void lstm_main(
    const void* __restrict__ xv, const void* __restrict__ Wxv,
    const void* __restrict__ Whv, const void* __restrict__ biasv,
    const void* __restrict__ c0v,
    void* __restrict__ outv, const int* __restrict__ modes,
    const int* __restrict__ rmask, u16* __restrict__ hist,
    u32* __restrict__ flags) {
  if ((modes[0] != 0) != BF16) return;

  // XCD-local decode: xcd = b&7 (round-robin heuristic), layer = xcd&3.
  const int xcd = blockIdx.x & 7;
  const int l = xcd & 3;
  const int s2 = (blockIdx.x >> 3) + ((xcd >> 2) << 5); // 0..63
  const int hb = s2 * 16;
  const int tid = threadIdx.x;
  const int wave = tid >> 6;
  const int lane = tid & 63;
  const bool xpart = (wave < 2);      // waves 0,1: y@Wx half; waves 2,3: h@Wh half
  const int krel = (wave & 1) * 512;  // K offset within this half's 1024 rows
  const int lrow = lane & 15;
  const int lk8 = (lane >> 4) * 8;

  // epilogue mapping: thread -> 2 adjacent n for one b
  const int eb = tid >> 3;            // 0..31  (batch row)
  const int n0 = (tid & 7) * 2;       // 0,2,..,14
  const int emt = eb >> 4, er = eb & 15;

  __shared__ float red[4][2][4][16][17]; // [wave][mtile][gate][row][col(+pad)]

  // ---- one-time weight preload: B-fragments B[k][n], n=lane&15, k=lk8+j ----
  short8 wfrag[4][16]; // [gate][ktile]
  {
    const size_t base = (size_t)l * NW * G4;
#pragma unroll
    for (int g = 0; g < 4; ++g) {
#pragma unroll
      for (int kt = 0; kt < 16; ++kt) {
        size_t off = base + (size_t)(krel + kt * 32 + lk8) * G4 + (size_t)(g * 1024 + hb + lrow);
        short8 v;
        if (BF16) {
          const u16* p = (xpart ? (const u16*)Wxv : (const u16*)Whv) + off;
#pragma unroll
          for (int j = 0; j < 8; ++j) v[j] = (short)p[(size_t)j * G4];
        } else {
          const float* p = (xpart ? (const float*)Wxv : (const float*)Whv) + off;
#pragma unroll
          for (int j = 0; j < 8; ++j) v[j] = (short)f2bf(p[(size_t)j * G4]);
        }
        wfrag[g][kt] = v;
      }
    }
  }

  // ---- bias preload for this thread's 2 cells ----
  float bias_r[4][2];
#pragma unroll
  for (int g = 0; g < 4; ++g)
#pragma unroll
    for (int j = 0; j < 2; ++j) {
      int bidx = l * G4 + g * 1024 + hb + n0 + j;
      bias_r[g][j] = BF16 ? bf2f(((const u16*)biasv)[bidx]) : ((const float*)biasv)[bidx];
    }

  float creg[2] = {0.f, 0.f};

  short8 z8;
#pragma unroll
  for (int j = 0; j < 8; ++j) z8[j] = 0;

#pragma unroll 1
  for (int t = 0; t < NT; ++t) {
    // ---- per-wave poll: each wave gates only ITS OWN loads ----
    if (xpart) {
      if (l > 0) {
        const u32* fp = &flags[((size_t)(l - 1) * NT + t) * 64 + lane];
        while (poll_load(fp) == 0) {}
      }
    } else {
      if (t > 0) {
        const u32* fp = &flags[((size_t)l * NT + (t - 1)) * 64 + lane];
        while (poll_load(fp) == 0) {}
      }
    }

    // ---- A sources (chunked layout) ----
    const u16* srcH = hist + ((size_t)l * 65 + t) * (64 * 512);             // h[l][t-1]
    const u16* srcY = hist + ((size_t)(l - 1) * 65 + (t + 1)) * (64 * 512); // h[l-1][t]
    const u16* srcXb = (const u16*)xv + (size_t)t * NB * NW;
    const float* srcXf = (const float*)xv + (size_t)t * NB * NW;

    int rm0 = 0, rm1 = 0;
    if (!xpart) {
      rm0 = rmask[t * NB + lrow];
      rm1 = rmask[t * NB + 16 + lrow];
    }

    f32x4 acc[2][4];
    f32x4 zf = {0.f, 0.f, 0.f, 0.f};
#pragma unroll
    for (int mt = 0; mt < 2; ++mt)
#pragma unroll
      for (int g = 0; g < 4; ++g) acc[mt][g] = zf;

#pragma unroll
    for (int half = 0; half < 2; ++half) {
      short8 af[8][2];
#pragma unroll
      for (int q = 0; q < 8; ++q) {
        int k = krel + (half * 8 + q) * 32 + lk8;
        short8 a0, a1;
        if (!xpart || l > 0) {
          const u16* src = xpart ? srcY : srcH;
          const u16* pc = src + (size_t)(k >> 4) * 512 + (k & 15);
          a0 = *(const short8*)(pc + lrow * 16);
          a1 = *(const short8*)(pc + (lrow + 16) * 16);
          if (!xpart) {
            if (rm0) a0 = z8;
            if (rm1) a1 = z8;
          }
        } else if (BF16) {
          a0 = *(const short8*)(srcXb + (size_t)lrow * NW + k);
          a1 = *(const short8*)(srcXb + (size_t)(lrow + 16) * NW + k);
        } else {
          const f32x4* p0 = (const f32x4*)(srcXf + (size_t)lrow * NW + k);
          const f32x4* p1 = (const f32x4*)(srcXf + (size_t)(lrow + 16) * NW + k);
          f32x4 x0a = p0[0], x0b = p0[1], x1a = p1[0], x1b = p1[1];
#pragma unroll
          for (int j = 0; j < 4; ++j) {
            a0[j] = (short)f2bf(x0a[j]);
            a0[j + 4] = (short)f2bf(x0b[j]);
            a1[j] = (short)f2bf(x1a[j]);
            a1[j + 4] = (short)f2bf(x1b[j]);
          }
        }
        af[q][0] = a0;
        af[q][1] = a1;
      }
#pragma unroll
      for (int q = 0; q < 8; ++q) {
        const int kt = half * 8 + q;
#pragma unroll
        for (int g = 0; g < 4; ++g) {
          acc[0][g] = __builtin_amdgcn_mfma_f32_16x16x32_bf16(af[q][0], wfrag[g][kt], acc[0][g], 0, 0, 0);
          acc[1][g] = __builtin_amdgcn_mfma_f32_16x16x32_bf16(af[q][1], wfrag[g][kt], acc[1][g], 0, 0, 0);
        }
      }
    }

    // ---- cross-wave reduce via LDS ----
#pragma unroll
    for (int mt = 0; mt < 2; ++mt)
#pragma unroll
      for (int g = 0; g < 4; ++g)
#pragma unroll
        for (int r2 = 0; r2 < 4; ++r2)
          red[wave][mt][g][(lane >> 4) * 4 + r2][lrow] = acc[mt][g][r2];
    __syncthreads();

    // ---- epilogue: this thread's 2 cells (eb, n0) (eb, n0+1) ----
    {
      int rm = rmask[t * NB + eb];
      float hn[2];
#pragma unroll
      for (int j = 0; j < 2; ++j) {
        int n = n0 + j;
        float gv[4];
#pragma unroll
        for (int g = 0; g < 4; ++g)
          gv[g] = red[0][emt][g][er][n] + red[1][emt][g][er][n] +
                  red[2][emt][g][er][n] + red[3][emt][g][er][n] + bias_r[g][j];
        float c_old = creg[j];
        if (t == 0) {
          int cidx = (l * NB + eb) * NW + hb + n;
          c_old = BF16 ? bf2f(((const u16*)c0v)[cidx]) : ((const float*)c0v)[cidx];
        }
        if (rm) c_old = 0.f;
        float ci = sigmoidf_(gv[0]);
        float cf = sigmoidf_(gv[1]);
        float cg = tanhfast(gv[2]);
        float co = sigmoidf_(gv[3]);
        float cn = cf * c_old + ci * cg;
        hn[j] = co * tanhfast(cn);
        creg[j] = cn;
      }
      // publish h chunk: WRITE-THROUGH stores (sc0 sc1)
      u32 hp = (u32)f2bf(hn[0]) | ((u32)f2bf(hn[1]) << 16);
      size_t hoff = (((size_t)l * 65 + (t + 1)) * 64 + s2) * 512 + (size_t)eb * 16 + n0;
      publish_store((u32*)(hist + hoff), hp);
      // y output (layer 3)
      if (l == NLAY - 1) {
        size_t oy = ((size_t)t * NB + eb) * NW + hb + n0;
        if (BF16) ((u32*)outv)[oy >> 1] = hp;
        else { ((float*)outv)[oy] = hn[0]; ((float*)outv)[oy + 1] = hn[1]; }
      }
      // final c/h outputs
      if (t == NT - 1) {
        size_t oc = (size_t)NT * NB * NW + ((size_t)l * NB + eb) * NW + hb + n0;
        size_t oh = oc + (size_t)NLAY * NB * NW;
        if (BF16) {
          u32 cp = (u32)f2bf(creg[0]) | ((u32)f2bf(creg[1]) << 16);
          ((u32*)outv)[oc >> 1] = cp;
          ((u32*)outv)[oh >> 1] = hp;
        } else {
          ((float*)outv)[oc] = creg[0];
          ((float*)outv)[oc + 1] = creg[1];
          ((float*)outv)[oh] = hn[0];
          ((float*)outv)[oh + 1] = hn[1];
        }
      }
    }

    // ---- drain own stores (MALL-acked), barrier, one write-through flag ----
    asm volatile("s_waitcnt vmcnt(0)" ::: "memory");
    __syncthreads();  // all chunk stores acked; also protects red[]
    if (tid == 0)
      publish_store(&flags[((size_t)l * NT + t) * 64 + s2], 1u);
  }
}

// ---------------------------------------------------------------------------
extern "C" void kernel_launch(void* const* d_in, const int* in_sizes, int n_in,
                              void* d_out, int out_size, void* d_ws, size_t ws_size,
                              hipStream_t stream) {
  const void* x = d_in[0];
  const void* resets = d_in[1];
  const void* c0 = d_in[2];
  const void* h0 = d_in[3];
  const void* Wx = d_in[4];
  const void* Wh = d_in[5];
  const void* bias = d_in[6];

  char* ws = (char*)d_ws;
  u16* hist = (u16*)(ws + HIST_OFF);
  u32* flags = (u32*)(ws + FLAGS_OFF);
  int* rmask = (int*)(ws + RMASK_OFF);
  int* modes = (int*)(ws + MODE_OFF);

  lstm_setup<<<1, 256, 0, stream>>>(x, resets, modes, rmask, flags);
  lstm_prep<true><<<512, 256, 0, stream>>>(h0, modes, hist);
  lstm_prep<false><<<512, 256, 0, stream>>>(h0, modes, hist);
  lstm_main<true><<<256, 256, 0, stream>>>(x, Wx, Wh, bias, c0, d_out, modes, rmask, hist, flags);
  lstm_main<false><<<256, 256, 0, stream>>>(x, Wx, Wh, bias, c0, d_out, modes, rmask, hist, flags);
}